// Round 13
// baseline (354.111 us; speedup 1.0000x reference)
//
#include <hip/hip_runtime.h>

typedef unsigned short u16;
typedef unsigned int u32;
typedef __bf16 bf16_t;
typedef bf16_t bf16x8 __attribute__((ext_vector_type(8)));
typedef float f32x4 __attribute__((ext_vector_type(4)));
typedef u32 u32x4 __attribute__((ext_vector_type(4)));
typedef u32 u32x2 __attribute__((ext_vector_type(2)));

#define BATCH 8
#define CH 128
#define NSP 4096  // 64*64 spatial
#define LOG2E 1.44269504088896f

static __device__ __forceinline__ u16 f2bf(float f) {
  u32 u = __builtin_bit_cast(u32, f);
  u32 r = u + 0x7FFFu + ((u >> 16) & 1u);  // RNE
  return (u16)(r >> 16);
}

static __device__ __forceinline__ bf16x8 ld_bf8(const u16* p) {
  return __builtin_bit_cast(bf16x8, *(const u32x4*)p);
}

static __device__ __forceinline__ f32x4 mfma16(bf16x8 a, bf16x8 b, f32x4 c) {
  return __builtin_amdgcn_mfma_f32_16x16x32_bf16(a, b, c, 0, 0, 0);
}

static __device__ __forceinline__ u32 cvt_pk(float lo, float hi) {
  u32 r;
  asm("v_cvt_pk_bf16_f32 %0, %1, %2" : "=v"(r) : "v"(lo), "v"(hi));
  return r;
}

static __device__ __forceinline__ float fast_exp2(float x) {
#if __has_builtin(__builtin_amdgcn_exp2f)
  return __builtin_amdgcn_exp2f(x);
#else
  return exp2f(x);
#endif
}

// ---------------- GroupNorm stats (+ fused weight fp32->bf16 convert) ----------------
__global__ __launch_bounds__(256) void gn_stats_kernel(const float* __restrict__ x,
                                                       float* __restrict__ stats,
                                                       const float* __restrict__ wq,
                                                       const float* __restrict__ wk,
                                                       const float* __restrict__ wv,
                                                       const float* __restrict__ wo,
                                                       u16* __restrict__ wbf) {
  int bg = blockIdx.x;  // 0..255
  {
    int widx = bg * 256 + threadIdx.x;
    int m = widx >> 14, r = widx & 16383;
    const float* s = (m == 0) ? wq : (m == 1) ? wk : (m == 2) ? wv : wo;
    wbf[widx] = f2bf(s[r]);
  }
  const float4* p = (const float4*)(x + (size_t)bg * 16384);
  float s = 0.f, ss = 0.f;
  for (int i = threadIdx.x; i < 4096; i += 256) {
    float4 v = p[i];
    s += v.x + v.y + v.z + v.w;
    ss += v.x * v.x + v.y * v.y + v.z * v.z + v.w * v.w;
  }
  for (int off = 32; off; off >>= 1) {
    s += __shfl_xor(s, off);
    ss += __shfl_xor(ss, off);
  }
  __shared__ float rs[4], rss[4];
  int wave = threadIdx.x >> 6;
  if ((threadIdx.x & 63) == 0) { rs[wave] = s; rss[wave] = ss; }
  __syncthreads();
  if (threadIdx.x == 0) {
    s = rs[0] + rs[1] + rs[2] + rs[3];
    ss = rss[0] + rss[1] + rss[2] + rss[3];
    float mean = s * (1.f / 16384.f);
    float var = ss * (1.f / 16384.f) - mean * mean;
    stats[2 * bg] = mean;
    stats[2 * bg + 1] = rsqrtf(var + 1e-5f);
  }
}

// ---------------- GN apply + transpose (b,c,n) -> xd (b,n,c) bf16 ----------------
__global__ __launch_bounds__(256) void gn_apply_kernel(const float* __restrict__ x,
                                                       const float* __restrict__ stats,
                                                       const float* __restrict__ gnw,
                                                       const float* __restrict__ gnb,
                                                       u16* __restrict__ xd) {
  __shared__ float tile[32][129];
  __shared__ float sc[128], sh[128];
  int b = blockIdx.y, n0 = blockIdx.x * 32;
  int t = threadIdx.x;
  if (t < 128) {
    float mean = stats[2 * (b * 32 + (t >> 2))];
    float rstd = stats[2 * (b * 32 + (t >> 2)) + 1];
    float w = gnw[t];
    sc[t] = rstd * w;
    sh[t] = gnb[t] - mean * rstd * w;
  }
  const float* xb = x + (size_t)b * (CH * NSP);
#pragma unroll
  for (int r = 0; r < 16; ++r) {
    int e = t + r * 256;
    int c = e >> 5, j = e & 31;
    tile[j][c] = xb[(size_t)c * NSP + n0 + j];
  }
  __syncthreads();
  u16* xdb = xd + ((size_t)b * NSP + n0) * CH;
#pragma unroll
  for (int r = 0; r < 16; ++r) {
    int e = t + r * 256;
    int j = e >> 7, c = e & 127;
    xdb[(size_t)j * CH + c] = f2bf(tile[j][c] * sc[c] + sh[c]);
  }
}

// ---------------- fused QKV projections ----------------
// q,k: (b,n,c) bf16 (plain); v: (b,c,n) bf16 (plain); q pre-scaled log2e/sqrt(C)
__global__ __launch_bounds__(256) void qkv_kernel(const u16* __restrict__ xd,
                                                  const u16* __restrict__ wqb,
                                                  const u16* __restrict__ wkb,
                                                  const u16* __restrict__ wvb,
                                                  const float* __restrict__ bq,
                                                  const float* __restrict__ bk,
                                                  const float* __restrict__ bv,
                                                  u16* __restrict__ q, u16* __restrict__ k,
                                                  u16* __restrict__ v) {
  int b = blockIdx.y;
  int wave = threadIdx.x >> 6, lane = threadIdx.x & 63;
  int lr = lane & 15, lg = lane >> 4;
  int n_base = blockIdx.x * 64 + wave * 16;
  const u16* xrow = xd + ((size_t)b * NSP + n_base + lr) * CH;
  f32x4 accq[8] = {}, acck[8] = {}, accv[8] = {};
#pragma unroll
  for (int kk = 0; kk < 4; ++kk) {
    int coff = kk * 32 + lg * 8;
    bf16x8 xa = ld_bf8(xrow + coff);
#pragma unroll
    for (int ot = 0; ot < 8; ++ot) {
      int woff = (ot * 16 + lr) * CH + coff;
      bf16x8 wqf = ld_bf8(wqb + woff);
      bf16x8 wkf = ld_bf8(wkb + woff);
      bf16x8 wvf = ld_bf8(wvb + woff);
      accq[ot] = mfma16(xa, wqf, accq[ot]);
      acck[ot] = mfma16(xa, wkf, acck[ot]);
      accv[ot] = mfma16(wvf, xa, accv[ot]);
    }
  }
  const float qscale = 0.08838834764831845f * LOG2E;  // log2e/sqrt(128)
#pragma unroll
  for (int ot = 0; ot < 8; ++ot) {
    int o_col = ot * 16 + lr;
    float bqv = bq[o_col], bkv = bk[o_col];
#pragma unroll
    for (int r = 0; r < 4; ++r) {
      int nrow = n_base + lg * 4 + r;
      size_t off = ((size_t)b * NSP + nrow) * CH + o_col;
      q[off] = f2bf((accq[ot][r] + bqv) * qscale);
      k[off] = f2bf(acck[ot][r] + bkv);
    }
    int n_col = n_base + lr;
#pragma unroll
    for (int r = 0; r < 4; ++r) {
      int o_row = ot * 16 + lg * 4 + r;
      v[((size_t)b * CH + o_row) * NSP + n_col] = f2bf(accv[ot][r] + bv[o_row]);
    }
  }
}

// ---------------- flash attention (no-max, KV-split=4, reg-staged padded LDS) --------
// r6 structure (measured 86us at 2 blocks/CU grid-limited), now at 4 blocks/CU:
// grid 1024 (b=id&7 XCD-local, 32 qblks, 4 splits), __launch_bounds__(256,4).
// 4 waves x 32 q-rows; KV tile 64; 16 iters/block. K,V loaded global->regs a full
// iteration ahead, written to single-buffered padded LDS (K stride 136, V stride 72;
// all ds ops bank-quad-spread). V written fragment-contiguous. l reduced at epilogue.
#define KSTRIDE 136  // 128 + 8 u16 pad
#define VSTRIDE 72   // 64 + 8 u16 pad
__global__ __launch_bounds__(256, 4) void attn_kernel(const u16* __restrict__ q,
                                                      const u16* __restrict__ k,
                                                      const u16* __restrict__ v,
                                                      u16* __restrict__ part0,
                                                      u16* __restrict__ part1,
                                                      u16* __restrict__ part2,
                                                      u16* __restrict__ part3,
                                                      float* __restrict__ lbuf) {
  __shared__ __align__(16) u16 kbuf[64 * KSTRIDE];  // 17408 B
  __shared__ __align__(16) u16 vbuf[128 * VSTRIDE]; // 18432 B
  int id = blockIdx.x;
  int b = id & 7;
  int qblk = (id >> 3) & 31;
  int split = id >> 8;  // 0..3
  int wave = threadIdx.x >> 6, lane = threadIdx.x & 63;
  int lr = lane & 15, lg = lane >> 4;
  int i_base = qblk * 128 + wave * 32;
  int t0 = split * 16, t1 = t0 + 16;

  const u16* kg = k + (size_t)b * NSP * CH;
  const u16* vg = v + (size_t)b * CH * NSP;

  // Q fragments (B-operand: q-row at lane&15), 2 q-tiles x 4 k-chunks
  bf16x8 qa[2][4];
#pragma unroll
  for (int qt = 0; qt < 2; ++qt) {
    const u16* qrow = q + ((size_t)b * NSP + i_base + qt * 16 + lr) * CH;
#pragma unroll
    for (int kk = 0; kk < 4; ++kk) qa[qt][kk] = ld_bf8(qrow + kk * 32 + lg * 8);
  }

  // ---- K staging: instr m covers rows wave*16 + m*4 + (lane>>4), chunk lane&15 ----
  int kgo[4], klo[4];
#pragma unroll
  for (int m = 0; m < 4; ++m) {
    int kr = wave * 16 + m * 4 + (lane >> 4);
    kgo[m] = kr * CH + (lane & 15) * 8;       // global (u16), + t*64*CH per tile
    klo[m] = kr * KSTRIDE + (lane & 15) * 8;  // LDS (u16)
  }
  // ---- V staging: instr w covers rows c = wave*32 + w*8 + (lane>>3), chunk f=lane&7.
  // LDS chunk f holds granules {p, p+4}, p = (f>>2)*8 + (f&3)  (granule = 4 u16).
  int vgo[4][2], vlo[4];
  {
    int f = lane & 7;
    int p = ((lane >> 2) & 1) * 8 + (lane & 3);
#pragma unroll
    for (int w = 0; w < 4; ++w) {
      int c = wave * 32 + w * 8 + (lane >> 3);
      vgo[w][0] = c * NSP + p * 4;        // + t*64 per tile
      vgo[w][1] = c * NSP + (p + 4) * 4;
      vlo[w] = c * VSTRIDE + f * 8;
    }
  }

  u32x4 kstg[4];
  u32x2 vstg[4][2];
  auto KLOAD = [&](int t) {
    const u16* kt = kg + (size_t)t * (64 * CH);
#pragma unroll
    for (int m = 0; m < 4; ++m) kstg[m] = *(const u32x4*)(kt + kgo[m]);
  };
  auto VLOAD = [&](int t) {
    const u16* vt = vg + t * 64;
#pragma unroll
    for (int w = 0; w < 4; ++w) {
      vstg[w][0] = *(const u32x2*)(vt + vgo[w][0]);
      vstg[w][1] = *(const u32x2*)(vt + vgo[w][1]);
    }
  };
  auto KVWRITE = [&]() {
#pragma unroll
    for (int m = 0; m < 4; ++m) *(u32x4*)(kbuf + klo[m]) = kstg[m];
#pragma unroll
    for (int w = 0; w < 4; ++w) {
      u32x4 d = {vstg[w][0][0], vstg[w][0][1], vstg[w][1][0], vstg[w][1][1]};
      *(u32x4*)(vbuf + vlo[w]) = d;
    }
  };

  KLOAD(t0);
  VLOAD(t0);

  f32x4 oacc[2][8] = {};
  float lsum[2] = {0.f, 0.f};

  for (int t = t0; t < t1; ++t) {
    asm volatile("s_waitcnt vmcnt(0)" ::: "memory");  // K(t),V(t) regs ready (issued t-1)
    __builtin_amdgcn_s_barrier();                     // all waves done reading tile t-1
    KVWRITE();
    if (t + 1 < t1) {  // fire-and-forget prefetch; a full iteration to complete
      KLOAD(t + 1);
      VLOAD(t + 1);
    }
    asm volatile("s_waitcnt lgkmcnt(0)" ::: "memory");  // my ds_writes drained
    __builtin_amdgcn_s_barrier();                       // tile t visible to all waves
    __builtin_amdgcn_sched_barrier(0);

    // ---- S^T = K Q^T : lane holds 16 scores for q-row lr (per qt) ----
    f32x4 s[2][4] = {};
    __builtin_amdgcn_s_setprio(1);
#pragma unroll
    for (int kk = 0; kk < 4; ++kk) {
#pragma unroll
      for (int jt = 0; jt < 4; ++jt) {
        int row = jt * 16 + lr;
        bf16x8 kf = ld_bf8(kbuf + row * KSTRIDE + (kk * 4 + lg) * 8);
        s[0][jt] = mfma16(kf, qa[0][kk], s[0][jt]);
        s[1][jt] = mfma16(kf, qa[1][kk], s[1][jt]);
      }
    }
    __builtin_amdgcn_s_setprio(0);

    // ---- P = exp2(S), in-lane l accumulation, pack to PV A-fragments ----
    u32x4 paw[2][2];
#pragma unroll
    for (int qt = 0; qt < 2; ++qt) {
      float sum = 0.f;
#pragma unroll
      for (int jt = 0; jt < 4; ++jt)
#pragma unroll
        for (int r = 0; r < 4; ++r) {
          float pv = fast_exp2(s[qt][jt][r]);
          s[qt][jt][r] = pv;
          sum += pv;
        }
      lsum[qt] += sum;
#pragma unroll
      for (int kk2 = 0; kk2 < 2; ++kk2) {
        paw[qt][kk2][0] = cvt_pk(s[qt][2 * kk2][0], s[qt][2 * kk2][1]);
        paw[qt][kk2][1] = cvt_pk(s[qt][2 * kk2][2], s[qt][2 * kk2][3]);
        paw[qt][kk2][2] = cvt_pk(s[qt][2 * kk2 + 1][0], s[qt][2 * kk2 + 1][1]);
        paw[qt][kk2][3] = cvt_pk(s[qt][2 * kk2 + 1][2], s[qt][2 * kk2 + 1][3]);
      }
    }

    // ---- O += P V : fragment-contiguous b128 reads, conflict-free ----
    __builtin_amdgcn_s_setprio(1);
#pragma unroll
    for (int kk2 = 0; kk2 < 2; ++kk2) {
      bf16x8 pa0 = __builtin_bit_cast(bf16x8, paw[0][kk2]);
      bf16x8 pa1 = __builtin_bit_cast(bf16x8, paw[1][kk2]);
#pragma unroll
      for (int ct = 0; ct < 8; ++ct) {
        int c = ct * 16 + lr;
        bf16x8 vf = ld_bf8(vbuf + c * VSTRIDE + (kk2 * 4 + lg) * 8);
        oacc[0][ct] = mfma16(pa0, vf, oacc[0][ct]);
        oacc[1][ct] = mfma16(pa1, vf, oacc[1][ct]);
      }
    }
    __builtin_amdgcn_s_setprio(0);
  }

  // ---- epilogue: reduce l across lane groups; write unnormalized partial ----
  u16* pdst = (split == 0) ? part0 : (split == 1) ? part1 : (split == 2) ? part2 : part3;
  float* ldst = lbuf + (size_t)split * (BATCH * NSP) + (size_t)b * NSP;
#pragma unroll
  for (int qt = 0; qt < 2; ++qt) {
    lsum[qt] += __shfl_xor(lsum[qt], 16);
    lsum[qt] += __shfl_xor(lsum[qt], 32);
    if (lg == 0) ldst[i_base + qt * 16 + lr] = lsum[qt];
#pragma unroll
    for (int r = 0; r < 4; ++r) {
      int i = i_base + qt * 16 + lg * 4 + r;
      u16* row = pdst + ((size_t)b * NSP + i) * CH;
#pragma unroll
      for (int ct = 0; ct < 8; ++ct) row[ct * 16 + lr] = f2bf(oacc[qt][ct][r]);
    }
  }
}

// ---------------- combine four KV-split partials (serializes d_out scratch use) ------
__global__ __launch_bounds__(256) void combine_kernel(const u16* __restrict__ p0,
                                                      const u16* __restrict__ p1,
                                                      const u16* __restrict__ p2,
                                                      const u16* __restrict__ p3,
                                                      const float* __restrict__ lbuf,
                                                      u16* __restrict__ omid) {
  int idx = blockIdx.x * 256 + threadIdx.x;  // 0..524287
  int row = idx >> 4, coff = (idx & 15) * 8;
  const int BN = BATCH * NSP;
  float l = lbuf[row] + lbuf[BN + row] + lbuf[2 * BN + row] + lbuf[3 * BN + row];
  float inv = 1.f / l;
  bf16x8 a = ld_bf8(p0 + (size_t)row * CH + coff);
  bf16x8 bb = ld_bf8(p1 + (size_t)row * CH + coff);
  bf16x8 cc = ld_bf8(p2 + (size_t)row * CH + coff);
  bf16x8 dd = ld_bf8(p3 + (size_t)row * CH + coff);
  u16 outv[8];
#pragma unroll
  for (int e = 0; e < 8; ++e)
    outv[e] = f2bf(((float)a[e] + (float)bb[e] + (float)cc[e] + (float)dd[e]) * inv);
  *(u32x4*)(omid + (size_t)row * CH + coff) = *(const u32x4*)outv;
}

// ---------------- output projection + residual ----------------
__global__ __launch_bounds__(256) void proj_kernel(const u16* __restrict__ omid,
                                                   const u16* __restrict__ wob,
                                                   const float* __restrict__ bo,
                                                   const float* __restrict__ gamma,
                                                   const float* __restrict__ x,
                                                   float* __restrict__ out) {
  int b = blockIdx.y;
  int wave = threadIdx.x >> 6, lane = threadIdx.x & 63;
  int lr = lane & 15, lg = lane >> 4;
  int n_base = blockIdx.x * 64 + wave * 16;
  const u16* orow = omid + ((size_t)b * NSP + n_base + lr) * CH;
  f32x4 acc[8] = {};
#pragma unroll
  for (int kk = 0; kk < 4; ++kk) {
    int coff = kk * 32 + lg * 8;
    bf16x8 ofrag = ld_bf8(orow + coff);
#pragma unroll
    for (int ot = 0; ot < 8; ++ot) {
      bf16x8 wf = ld_bf8(wob + (ot * 16 + lr) * CH + coff);
      acc[ot] = mfma16(wf, ofrag, acc[ot]);
    }
  }
  float g = gamma[0];
  int n_col = n_base + lr;
#pragma unroll
  for (int ot = 0; ot < 8; ++ot) {
#pragma unroll
    for (int r = 0; r < 4; ++r) {
      int o_row = ot * 16 + lg * 4 + r;
      size_t off = ((size_t)b * CH + o_row) * NSP + n_col;
      out[off] = x[off] + g * (acc[ot][r] + bo[o_row]);
    }
  }
}

extern "C" void kernel_launch(void* const* d_in, const int* in_sizes, int n_in,
                              void* d_out, int out_size, void* d_ws, size_t ws_size,
                              hipStream_t stream) {
  const float* x = (const float*)d_in[0];
  const float* gnw = (const float*)d_in[1];
  const float* gnb = (const float*)d_in[2];
  const float* wq = (const float*)d_in[3];
  const float* bq = (const float*)d_in[4];
  const float* wk = (const float*)d_in[5];
  const float* bk = (const float*)d_in[6];
  const float* wv = (const float*)d_in[7];
  const float* bv = (const float*)d_in[8];
  const float* wo = (const float*)d_in[9];
  const float* bo = (const float*)d_in[10];
  const float* gamma = (const float*)d_in[11];
  float* out = (float*)d_out;

  const size_t BUF = (size_t)BATCH * NSP * CH * sizeof(u16);  // 8 MB
  char* ws = (char*)d_ws;
  u16* wbf = (u16*)ws;             // 4 x 128x128 bf16 = 128KB
  float* stats = (float*)(ws + 131072);
  u16* xd = (u16*)(ws + 262144);   // x_dash (b,n,c); later: split0 partial O
  u16* qb = (u16*)(ws + 262144 + BUF);
  u16* kb = (u16*)(ws + 262144 + 2 * BUF);  // later: combined O_mid
  u16* vb = (u16*)(ws + 262144 + 3 * BUF);
  float* lbuf = (float*)(ws + 262144 + 4 * BUF);  // 4 x 32768 f32 = 512KB
  const size_t need = 262144 + 4 * BUF + 524288;
  if (ws_size < need) return;
  // part1: prefer extra ws space; else reuse qb (Q read only in attn prologue; grid
  // 1024 at 4 blocks/CU: epilogue writes land long after all Q prologue reads)
  u16* part1 = (ws_size >= need + BUF) ? (u16*)(ws + need) : qb;
  // part2/part3 live in d_out (16 MB f32 output == exactly 2 x 8MB bf16 partials);
  // combine_kernel consumes them BEFORE proj_kernel writes d_out (stream-serialized).
  u16* part2 = (u16*)d_out;
  u16* part3 = (u16*)d_out + (size_t)BATCH * NSP * CH;

  gn_stats_kernel<<<256, 256, 0, stream>>>(x, stats, wq, wk, wv, wo, wbf);
  gn_apply_kernel<<<dim3(128, 8), 256, 0, stream>>>(x, stats, gnw, gnb, xd);
  qkv_kernel<<<dim3(64, 8), 256, 0, stream>>>(xd, wbf, wbf + 16384, wbf + 32768,
                                              bq, bk, bv, qb, kb, vb);
  attn_kernel<<<1024, 256, 0, stream>>>(qb, kb, vb, xd, part1, part2, part3, lbuf);
  combine_kernel<<<2048, 256, 0, stream>>>(xd, part1, part2, part3, lbuf, kb);
  proj_kernel<<<dim3(64, 8), 256, 0, stream>>>(kb, wbf + 49152, bo, gamma, x, out);
}

// Round 14
// 135.301 us; speedup vs baseline: 2.6172x; 2.6172x over previous
//
#include <hip/hip_runtime.h>

typedef unsigned short u16;
typedef unsigned int u32;
typedef __bf16 bf16_t;
typedef bf16_t bf16x8 __attribute__((ext_vector_type(8)));
typedef float f32x4 __attribute__((ext_vector_type(4)));
typedef u32 u32x4 __attribute__((ext_vector_type(4)));
typedef u32 u32x2 __attribute__((ext_vector_type(2)));

#define BATCH 8
#define CH 128
#define NSP 4096  // 64*64 spatial
#define LOG2E 1.44269504088896f

static __device__ __forceinline__ u16 f2bf(float f) {
  u32 u = __builtin_bit_cast(u32, f);
  u32 r = u + 0x7FFFu + ((u >> 16) & 1u);  // RNE
  return (u16)(r >> 16);
}

static __device__ __forceinline__ bf16x8 ld_bf8(const u16* p) {
  return __builtin_bit_cast(bf16x8, *(const u32x4*)p);
}

static __device__ __forceinline__ f32x4 mfma16(bf16x8 a, bf16x8 b, f32x4 c) {
  return __builtin_amdgcn_mfma_f32_16x16x32_bf16(a, b, c, 0, 0, 0);
}

static __device__ __forceinline__ u32 cvt_pk(float lo, float hi) {
  u32 r;
  asm("v_cvt_pk_bf16_f32 %0, %1, %2" : "=v"(r) : "v"(lo), "v"(hi));
  return r;
}

static __device__ __forceinline__ float fast_exp2(float x) {
#if __has_builtin(__builtin_amdgcn_exp2f)
  return __builtin_amdgcn_exp2f(x);
#else
  return exp2f(x);
#endif
}

// ---------------- GroupNorm stats (+ fused weight fp32->bf16 convert) ----------------
__global__ __launch_bounds__(256) void gn_stats_kernel(const float* __restrict__ x,
                                                       float* __restrict__ stats,
                                                       const float* __restrict__ wq,
                                                       const float* __restrict__ wk,
                                                       const float* __restrict__ wv,
                                                       const float* __restrict__ wo,
                                                       u16* __restrict__ wbf) {
  int bg = blockIdx.x;  // 0..255
  {
    int widx = bg * 256 + threadIdx.x;
    int m = widx >> 14, r = widx & 16383;
    const float* s = (m == 0) ? wq : (m == 1) ? wk : (m == 2) ? wv : wo;
    wbf[widx] = f2bf(s[r]);
  }
  const float4* p = (const float4*)(x + (size_t)bg * 16384);
  float s = 0.f, ss = 0.f;
  for (int i = threadIdx.x; i < 4096; i += 256) {
    float4 v = p[i];
    s += v.x + v.y + v.z + v.w;
    ss += v.x * v.x + v.y * v.y + v.z * v.z + v.w * v.w;
  }
  for (int off = 32; off; off >>= 1) {
    s += __shfl_xor(s, off);
    ss += __shfl_xor(ss, off);
  }
  __shared__ float rs[4], rss[4];
  int wave = threadIdx.x >> 6;
  if ((threadIdx.x & 63) == 0) { rs[wave] = s; rss[wave] = ss; }
  __syncthreads();
  if (threadIdx.x == 0) {
    s = rs[0] + rs[1] + rs[2] + rs[3];
    ss = rss[0] + rss[1] + rss[2] + rss[3];
    float mean = s * (1.f / 16384.f);
    float var = ss * (1.f / 16384.f) - mean * mean;
    stats[2 * bg] = mean;
    stats[2 * bg + 1] = rsqrtf(var + 1e-5f);
  }
}

// ---------------- fused GN-apply + QKV projections ----------------
// Reads x (b,c,n) directly, applies GN, transposes via f32 LDS tile, then the 3
// GEMMs. q,k: (b,n,c) bf16 (q pre-scaled by log2e/sqrt(C)); v: (b,c,n) bf16.
__global__ __launch_bounds__(256) void qkv_kernel(const float* __restrict__ x,
                                                  const float* __restrict__ stats,
                                                  const float* __restrict__ gnw,
                                                  const float* __restrict__ gnb,
                                                  const u16* __restrict__ wqb,
                                                  const u16* __restrict__ wkb,
                                                  const u16* __restrict__ wvb,
                                                  const float* __restrict__ bq,
                                                  const float* __restrict__ bk,
                                                  const float* __restrict__ bv,
                                                  u16* __restrict__ q, u16* __restrict__ k,
                                                  u16* __restrict__ v) {
  __shared__ float tile[64][132];  // x^T tile (n-local, c) f32; stride 132 keeps b128 reads clean
  __shared__ float sc[128], sh[128];
  int b = blockIdx.y;
  int n0 = blockIdx.x * 64;
  int t = threadIdx.x;
  if (t < 128) {
    float mean = stats[2 * (b * 32 + (t >> 2))];
    float rstd = stats[2 * (b * 32 + (t >> 2)) + 1];
    float w = gnw[t];
    sc[t] = rstd * w;
    sh[t] = gnb[t] - mean * rstd * w;
  }
  __syncthreads();
  const float4* xb4 = (const float4*)(x + (size_t)b * CH * NSP);
#pragma unroll
  for (int i = 0; i < 8; ++i) {
    int idx = t + i * 256;
    int c = idx >> 4, j4 = idx & 15;
    float4 vv = xb4[(size_t)c * (NSP / 4) + (n0 >> 2) + j4];
    float s_ = sc[c], h_ = sh[c];
    tile[j4 * 4 + 0][c] = vv.x * s_ + h_;
    tile[j4 * 4 + 1][c] = vv.y * s_ + h_;
    tile[j4 * 4 + 2][c] = vv.z * s_ + h_;
    tile[j4 * 4 + 3][c] = vv.w * s_ + h_;
  }
  __syncthreads();

  int wave = t >> 6, lane = t & 63;
  int lr = lane & 15, lg = lane >> 4;
  int n_base = n0 + wave * 16;
  int row = wave * 16 + lr;

  bf16x8 xfr[4];
#pragma unroll
  for (int kk = 0; kk < 4; ++kk) {
    const float* p = &tile[row][kk * 32 + lg * 8];
    f32x4 lo = *(const f32x4*)p;
    f32x4 hi = *(const f32x4*)(p + 4);
    u32x4 xw = {cvt_pk(lo[0], lo[1]), cvt_pk(lo[2], lo[3]),
                cvt_pk(hi[0], hi[1]), cvt_pk(hi[2], hi[3])};
    xfr[kk] = __builtin_bit_cast(bf16x8, xw);
  }

  f32x4 accq[8] = {}, acck[8] = {}, accv[8] = {};
#pragma unroll
  for (int kk = 0; kk < 4; ++kk) {
    int coff = kk * 32 + lg * 8;
    bf16x8 xa = xfr[kk];
#pragma unroll
    for (int ot = 0; ot < 8; ++ot) {
      int woff = (ot * 16 + lr) * CH + coff;
      bf16x8 wqf = ld_bf8(wqb + woff);
      bf16x8 wkf = ld_bf8(wkb + woff);
      bf16x8 wvf = ld_bf8(wvb + woff);
      accq[ot] = mfma16(xa, wqf, accq[ot]);
      acck[ot] = mfma16(xa, wkf, acck[ot]);
      accv[ot] = mfma16(wvf, xa, accv[ot]);
    }
  }
  const float qscale = 0.08838834764831845f * LOG2E;  // log2e/sqrt(128)
#pragma unroll
  for (int ot = 0; ot < 8; ++ot) {
    int o_col = ot * 16 + lr;
    float bqv = bq[o_col], bkv = bk[o_col];
#pragma unroll
    for (int r = 0; r < 4; ++r) {
      int nrow = n_base + lg * 4 + r;
      size_t off = ((size_t)b * NSP + nrow) * CH + o_col;
      q[off] = f2bf((accq[ot][r] + bqv) * qscale);
      k[off] = f2bf(acck[ot][r] + bkv);
    }
    int n_col = n_base + lr;
#pragma unroll
    for (int r = 0; r < 4; ++r) {
      int o_row = ot * 16 + lg * 4 + r;
      v[((size_t)b * CH + o_row) * NSP + n_col] = f2bf(accv[ot][r] + bv[o_row]);
    }
  }
}

// ---------------- flash attention (no-max, KV-split=2, reg-staged, LDS DOUBLE-buffer) -
// r6 structure (86us verified) + double-buffered padded LDS -> ONE barrier/iter:
// KVWRITE targets the opposite buffer, so no WAR with current readers; the single
// end-of-iter barrier (after lgkmcnt drain) publishes tile t+1 before iter t+1 reads.
// K,V loaded global->regs a FULL iteration ahead (vmcnt(0) covered by compute).
// Padded strides (K 136, V 72 u16) keep all ds ops at r6's measured behavior.
// l: in-lane accumulation, reduced once at epilogue.
#define KSTRIDE 136  // 128 + 8 u16 pad
#define VSTRIDE 72   // 64 + 8 u16 pad
__global__ __launch_bounds__(256, 2) void attn_kernel(const u16* __restrict__ q,
                                                      const u16* __restrict__ k,
                                                      const u16* __restrict__ v,
                                                      u16* __restrict__ part0,
                                                      u16* __restrict__ part1,
                                                      float* __restrict__ lbuf) {
  __shared__ __align__(16) u16 kbuf[2][64 * KSTRIDE];  // 2 x 17408 B
  __shared__ __align__(16) u16 vbuf[2][128 * VSTRIDE]; // 2 x 18432 B
  int id = blockIdx.x;
  int b = id & 7;
  int qblk = (id >> 3) & 31;
  int split = id >> 8;  // 0 or 1
  int wave = threadIdx.x >> 6, lane = threadIdx.x & 63;
  int lr = lane & 15, lg = lane >> 4;
  int i_base = qblk * 128 + wave * 32;
  int t0 = split * 32, t1 = t0 + 32;

  const u16* kg = k + (size_t)b * NSP * CH;
  const u16* vg = v + (size_t)b * CH * NSP;

  // Q fragments (B-operand: q-row at lane&15), 2 q-tiles x 4 k-chunks
  bf16x8 qa[2][4];
#pragma unroll
  for (int qt = 0; qt < 2; ++qt) {
    const u16* qrow = q + ((size_t)b * NSP + i_base + qt * 16 + lr) * CH;
#pragma unroll
    for (int kk = 0; kk < 4; ++kk) qa[qt][kk] = ld_bf8(qrow + kk * 32 + lg * 8);
  }

  // ---- K staging: instr m covers rows wave*16 + m*4 + (lane>>4), chunk lane&15 ----
  int kgo[4], klo[4];
#pragma unroll
  for (int m = 0; m < 4; ++m) {
    int kr = wave * 16 + m * 4 + (lane >> 4);
    kgo[m] = kr * CH + (lane & 15) * 8;       // global (u16), + t*64*CH per tile
    klo[m] = kr * KSTRIDE + (lane & 15) * 8;  // LDS (u16)
  }
  // ---- V staging: instr w covers rows c = wave*32 + w*8 + (lane>>3), chunk f=lane&7.
  // LDS chunk f holds granules {p, p+4}, p = (f>>2)*8 + (f&3)  (granule = 4 u16).
  int vgo[4][2], vlo[4];
  {
    int f = lane & 7;
    int p = ((lane >> 2) & 1) * 8 + (lane & 3);
#pragma unroll
    for (int w = 0; w < 4; ++w) {
      int c = wave * 32 + w * 8 + (lane >> 3);
      vgo[w][0] = c * NSP + p * 4;        // + t*64 per tile
      vgo[w][1] = c * NSP + (p + 4) * 4;
      vlo[w] = c * VSTRIDE + f * 8;
    }
  }

  u32x4 kstg[4];
  u32x2 vstg[4][2];
  auto KLOAD = [&](int t) {
    const u16* kt = kg + (size_t)t * (64 * CH);
#pragma unroll
    for (int m = 0; m < 4; ++m) kstg[m] = *(const u32x4*)(kt + kgo[m]);
  };
  auto VLOAD = [&](int t) {
    const u16* vt = vg + t * 64;
#pragma unroll
    for (int w = 0; w < 4; ++w) {
      vstg[w][0] = *(const u32x2*)(vt + vgo[w][0]);
      vstg[w][1] = *(const u32x2*)(vt + vgo[w][1]);
    }
  };
  auto KVWRITE = [&](int bi) {
    u16* kb2 = kbuf[bi];
    u16* vb2 = vbuf[bi];
#pragma unroll
    for (int m = 0; m < 4; ++m) *(u32x4*)(kb2 + klo[m]) = kstg[m];
#pragma unroll
    for (int w = 0; w < 4; ++w) {
      u32x4 d = {vstg[w][0][0], vstg[w][0][1], vstg[w][1][0], vstg[w][1][1]};
      *(u32x4*)(vb2 + vlo[w]) = d;
    }
  };

  // prologue: tile t0 into buf0; t0+1 loads in flight
  KLOAD(t0);
  VLOAD(t0);
  asm volatile("s_waitcnt vmcnt(0)" ::: "memory");
  KVWRITE(0);
  KLOAD(t0 + 1);
  VLOAD(t0 + 1);
  asm volatile("s_waitcnt lgkmcnt(0)" ::: "memory");
  __builtin_amdgcn_s_barrier();
  __builtin_amdgcn_sched_barrier(0);

  f32x4 oacc[2][8] = {};
  float lsum[2] = {0.f, 0.f};

  for (int t = t0; t < t1; ++t) {
    int cur = (t - t0) & 1;
    const u16* kb = kbuf[cur];
    const u16* vb = vbuf[cur];

    // ---- S^T = K Q^T : lane holds 16 scores for q-row lr (per qt) ----
    f32x4 s[2][4] = {};
    __builtin_amdgcn_s_setprio(1);
#pragma unroll
    for (int kk = 0; kk < 4; ++kk) {
#pragma unroll
      for (int jt = 0; jt < 4; ++jt) {
        int row = jt * 16 + lr;
        bf16x8 kf = ld_bf8(kb + row * KSTRIDE + (kk * 4 + lg) * 8);
        s[0][jt] = mfma16(kf, qa[0][kk], s[0][jt]);
        s[1][jt] = mfma16(kf, qa[1][kk], s[1][jt]);
      }
    }
    __builtin_amdgcn_s_setprio(0);

    // ---- P = exp2(S), in-lane l accumulation, pack to PV A-fragments ----
    u32x4 paw[2][2];
#pragma unroll
    for (int qt = 0; qt < 2; ++qt) {
      float sum = 0.f;
#pragma unroll
      for (int jt = 0; jt < 4; ++jt)
#pragma unroll
        for (int r = 0; r < 4; ++r) {
          float pv = fast_exp2(s[qt][jt][r]);
          s[qt][jt][r] = pv;
          sum += pv;
        }
      lsum[qt] += sum;
#pragma unroll
      for (int kk2 = 0; kk2 < 2; ++kk2) {
        paw[qt][kk2][0] = cvt_pk(s[qt][2 * kk2][0], s[qt][2 * kk2][1]);
        paw[qt][kk2][1] = cvt_pk(s[qt][2 * kk2][2], s[qt][2 * kk2][3]);
        paw[qt][kk2][2] = cvt_pk(s[qt][2 * kk2 + 1][0], s[qt][2 * kk2 + 1][1]);
        paw[qt][kk2][3] = cvt_pk(s[qt][2 * kk2 + 1][2], s[qt][2 * kk2 + 1][3]);
      }
    }

    // ---- O += P V : fragment-contiguous b128 reads ----
    __builtin_amdgcn_s_setprio(1);
#pragma unroll
    for (int kk2 = 0; kk2 < 2; ++kk2) {
      bf16x8 pa0 = __builtin_bit_cast(bf16x8, paw[0][kk2]);
      bf16x8 pa1 = __builtin_bit_cast(bf16x8, paw[1][kk2]);
#pragma unroll
      for (int ct = 0; ct < 8; ++ct) {
        int c = ct * 16 + lr;
        bf16x8 vf = ld_bf8(vb + c * VSTRIDE + (kk2 * 4 + lg) * 8);
        oacc[0][ct] = mfma16(pa0, vf, oacc[0][ct]);
        oacc[1][ct] = mfma16(pa1, vf, oacc[1][ct]);
      }
    }
    __builtin_amdgcn_s_setprio(0);

    if (t + 1 < t1) {
      asm volatile("s_waitcnt vmcnt(0)" ::: "memory");  // regs for t+1 arrived
      KVWRITE(cur ^ 1);                                 // write tile t+1 (other buffer)
      if (t + 2 < t1) {  // fire-and-forget: a full compute phase to land
        KLOAD(t + 2);
        VLOAD(t + 2);
      }
      asm volatile("s_waitcnt lgkmcnt(0)" ::: "memory");  // my ds_writes drained
      __builtin_amdgcn_s_barrier();                       // tile t+1 visible to all
      __builtin_amdgcn_sched_barrier(0);
    }
  }

  // ---- epilogue: reduce l across lane groups; write unnormalized partial ----
  u16* pdst = (split == 0) ? part0 : part1;
  float* ldst = lbuf + (size_t)split * (BATCH * NSP) + (size_t)b * NSP;
#pragma unroll
  for (int qt = 0; qt < 2; ++qt) {
    lsum[qt] += __shfl_xor(lsum[qt], 16);
    lsum[qt] += __shfl_xor(lsum[qt], 32);
    if (lg == 0) ldst[i_base + qt * 16 + lr] = lsum[qt];
#pragma unroll
    for (int r = 0; r < 4; ++r) {
      int i = i_base + qt * 16 + lg * 4 + r;
      u16* row = pdst + ((size_t)b * NSP + i) * CH;
#pragma unroll
      for (int ct = 0; ct < 8; ++ct) row[ct * 16 + lr] = f2bf(oacc[qt][ct][r]);
    }
  }
}

// ---------------- output projection + residual (combines the 2 KV-split partials) ----
__global__ __launch_bounds__(256) void proj_kernel(const u16* __restrict__ p0,
                                                   const u16* __restrict__ p1,
                                                   const float* __restrict__ lbuf,
                                                   const u16* __restrict__ wob,
                                                   const float* __restrict__ bo,
                                                   const float* __restrict__ gamma,
                                                   const float* __restrict__ x,
                                                   float* __restrict__ out) {
  int b = blockIdx.y;
  int wave = threadIdx.x >> 6, lane = threadIdx.x & 63;
  int lr = lane & 15, lg = lane >> 4;
  int n_base = blockIdx.x * 64 + wave * 16;
  int nrow = n_base + lr;
  float linv = 1.f / (lbuf[(size_t)b * NSP + nrow] +
                      lbuf[(size_t)BATCH * NSP + (size_t)b * NSP + nrow]);
  const u16* r0 = p0 + ((size_t)b * NSP + nrow) * CH;
  const u16* r1 = p1 + ((size_t)b * NSP + nrow) * CH;
  f32x4 acc[8] = {};
#pragma unroll
  for (int kk = 0; kk < 4; ++kk) {
    int coff = kk * 32 + lg * 8;
    bf16x8 a = ld_bf8(r0 + coff);
    bf16x8 bb = ld_bf8(r1 + coff);
    u32 w0 = cvt_pk(((float)a[0] + (float)bb[0]) * linv, ((float)a[1] + (float)bb[1]) * linv);
    u32 w1 = cvt_pk(((float)a[2] + (float)bb[2]) * linv, ((float)a[3] + (float)bb[3]) * linv);
    u32 w2 = cvt_pk(((float)a[4] + (float)bb[4]) * linv, ((float)a[5] + (float)bb[5]) * linv);
    u32 w3 = cvt_pk(((float)a[6] + (float)bb[6]) * linv, ((float)a[7] + (float)bb[7]) * linv);
    u32x4 wv = {w0, w1, w2, w3};
    bf16x8 ofrag = __builtin_bit_cast(bf16x8, wv);
#pragma unroll
    for (int ot = 0; ot < 8; ++ot) {
      bf16x8 wf = ld_bf8(wob + (ot * 16 + lr) * CH + coff);
      acc[ot] = mfma16(wf, ofrag, acc[ot]);
    }
  }
  float g = gamma[0];
  int n_col = n_base + lr;
#pragma unroll
  for (int ot = 0; ot < 8; ++ot) {
#pragma unroll
    for (int r = 0; r < 4; ++r) {
      int o_row = ot * 16 + lg * 4 + r;
      size_t off = ((size_t)b * CH + o_row) * NSP + n_col;
      out[off] = x[off] + g * (acc[ot][r] + bo[o_row]);
    }
  }
}

extern "C" void kernel_launch(void* const* d_in, const int* in_sizes, int n_in,
                              void* d_out, int out_size, void* d_ws, size_t ws_size,
                              hipStream_t stream) {
  const float* x = (const float*)d_in[0];
  const float* gnw = (const float*)d_in[1];
  const float* gnb = (const float*)d_in[2];
  const float* wq = (const float*)d_in[3];
  const float* bq = (const float*)d_in[4];
  const float* wk = (const float*)d_in[5];
  const float* bk = (const float*)d_in[6];
  const float* wv = (const float*)d_in[7];
  const float* bv = (const float*)d_in[8];
  const float* wo = (const float*)d_in[9];
  const float* bo = (const float*)d_in[10];
  const float* gamma = (const float*)d_in[11];
  float* out = (float*)d_out;

  const size_t BUF = (size_t)BATCH * NSP * CH * sizeof(u16);  // 8 MB
  char* ws = (char*)d_ws;
  u16* wbf = (u16*)ws;             // 4 x 128x128 bf16 = 128KB
  float* stats = (float*)(ws + 131072);
  u16* xd = (u16*)(ws + 262144);   // split0 partial O
  u16* qb = (u16*)(ws + 262144 + BUF);
  u16* kb = (u16*)(ws + 262144 + 2 * BUF);
  u16* vb = (u16*)(ws + 262144 + 3 * BUF);
  float* lbuf = (float*)(ws + 262144 + 4 * BUF);  // 2 x 32768 f32 = 256KB
  const size_t need = 262144 + 4 * BUF + 262144;
  if (ws_size < need) return;
  // split1 partial: prefer extra ws space; else reuse qb (Q read only in attn prologue;
  // grid=512 at 2 blocks/CU is fully co-resident, epilogue writes land long after reads)
  u16* part1 = (ws_size >= need + BUF) ? (u16*)(ws + need) : qb;

  gn_stats_kernel<<<256, 256, 0, stream>>>(x, stats, wq, wk, wv, wo, wbf);
  qkv_kernel<<<dim3(64, 8), 256, 0, stream>>>(x, stats, gnw, gnb, wbf, wbf + 16384,
                                              wbf + 32768, bq, bk, bv, qb, kb, vb);
  attn_kernel<<<512, 256, 0, stream>>>(qb, kb, vb, xd, part1, lbuf);
  proj_kernel<<<dim3(64, 8), 256, 0, stream>>>(xd, part1, lbuf, wbf + 49152, bo, gamma,
                                               x, out);
}